// Round 1
// baseline (1823.235 us; speedup 1.0000x reference)
//
#include <hip/hip_runtime.h>

#define NN 100000
#define HD 64

__global__ void deg_kernel(const int* __restrict__ dst, float* __restrict__ deg, int E) {
    int e = blockIdx.x * blockDim.x + threadIdx.x;
    if (e < E) atomicAdd(&deg[dst[e]], 1.0f);
}

__global__ void dinv_kernel(float* __restrict__ deg, int n) {
    int v = blockIdx.x * blockDim.x + threadIdx.x;
    if (v < n) deg[v] = rsqrtf(deg[v] + 1.0f);  // +1 = self loop
}

// H = X @ W  (X: [n,64], W: [64,64]) — 16 rows per block, 256 threads
__global__ void matmul64_kernel(const float* __restrict__ X, const float* __restrict__ W,
                                float* __restrict__ H) {
    __shared__ float Wl[64 * 64];
    __shared__ float Xs[16 * 64];
    int tid = threadIdx.x;
#pragma unroll
    for (int i = 0; i < 16; ++i) Wl[tid + 256 * i] = W[tid + 256 * i];
    int row0 = blockIdx.x * 16;
#pragma unroll
    for (int i = 0; i < 4; ++i) Xs[tid + 256 * i] = X[row0 * 64 + tid + 256 * i];
    __syncthreads();
    int c = tid & 63, rq = tid >> 6;
    float acc[4] = {0.f, 0.f, 0.f, 0.f};
    for (int k = 0; k < 64; ++k) {
        float w = Wl[k * 64 + c];
#pragma unroll
        for (int j = 0; j < 4; ++j) acc[j] += Xs[(rq * 4 + j) * 64 + k] * w;
    }
#pragma unroll
    for (int j = 0; j < 4; ++j) H[(row0 + rq * 4 + j) * 64 + c] = acc[j];
}

// one wave per edge (incl. self loops), lane = channel
__global__ void scatter_kernel(const float* __restrict__ H, const int* __restrict__ src,
                               const int* __restrict__ dst, const float* __restrict__ dinv,
                               float* __restrict__ agg, int E, int n) {
    int t = blockIdx.x * blockDim.x + threadIdx.x;
    int e = t >> 6;
    int c = t & 63;
    if (e < E) {
        int s = src[e], d = dst[e];
        float nm = dinv[s] * dinv[d];
        atomicAdd(&agg[(size_t)d * HD + c], H[(size_t)s * HD + c] * nm);
    } else if (e < E + n) {
        int v = e - E;
        float dv = dinv[v];
        atomicAdd(&agg[(size_t)v * HD + c], H[(size_t)v * HD + c] * dv * dv);
    }
}

__global__ void combine_kernel(const float* __restrict__ agg, const float* __restrict__ b,
                               float* __restrict__ xc, int total, int residual) {
    int i = blockIdx.x * blockDim.x + threadIdx.x;
    if (i < total) {
        float v = agg[i] + b[i & 63];
        if (residual) v += xc[i];
        xc[i] = fmaxf(v, 0.0f);
    }
}

// one wave per node: 3 dot products of length 64 via shuffle reduce
__global__ void final_kernel(const float* __restrict__ xc, const float* __restrict__ Wc,
                             const float* __restrict__ bc, float* __restrict__ out, int n) {
    int tid = threadIdx.x;
    int lane = tid & 63;
    int w = tid >> 6;
    int node = blockIdx.x * 4 + w;
    if (node >= n) return;
    float xv = xc[(size_t)node * HD + lane];
#pragma unroll
    for (int j = 0; j < 3; ++j) {
        float p = xv * Wc[lane * 3 + j];
#pragma unroll
        for (int off = 32; off > 0; off >>= 1) p += __shfl_down(p, off);
        if (lane == 0) out[node * 3 + j] = p + bc[j];
    }
}

extern "C" void kernel_launch(void* const* d_in, const int* in_sizes, int n_in,
                              void* d_out, int out_size, void* d_ws, size_t ws_size,
                              hipStream_t stream) {
    const float* x  = (const float*)d_in[0];
    const int*   ei = (const int*)d_in[1];
    const float* Ws = (const float*)d_in[2];
    const float* bs = (const float*)d_in[3];
    const float* Wc = (const float*)d_in[4];
    const float* bc = (const float*)d_in[5];
    float* out = (float*)d_out;

    int E = in_sizes[1] / 2;
    const int* src = ei;
    const int* dst = ei + E;

    float* ws   = (float*)d_ws;
    float* dinv = ws;                               // N floats (512K slot)
    float* h    = ws + (1 << 17);                   // N*64
    float* agg  = h + (size_t)NN * HD;              // N*64
    float* xc   = agg + (size_t)NN * HD;            // N*64

    hipMemsetAsync(dinv, 0, NN * sizeof(float), stream);
    deg_kernel<<<(E + 255) / 256, 256, 0, stream>>>(dst, dinv, E);
    dinv_kernel<<<(NN + 255) / 256, 256, 0, stream>>>(dinv, NN);

    const float* xin = x;
    for (int l = 0; l < 4; ++l) {
        matmul64_kernel<<<NN / 16, 256, 0, stream>>>(xin, Ws + (size_t)l * HD * HD, h);
        hipMemsetAsync(agg, 0, (size_t)NN * HD * sizeof(float), stream);
        int total = (E + NN) * HD;
        scatter_kernel<<<(total + 255) / 256, 256, 0, stream>>>(h, src, dst, dinv, agg, E, NN);
        combine_kernel<<<(NN * HD + 255) / 256, 256, 0, stream>>>(agg, bs + l * HD, xc, NN * HD, l > 0);
        xin = xc;
    }
    final_kernel<<<(NN + 3) / 4, 256, 0, stream>>>(xc, Wc, bc, out, NN);
}

// Round 2
// 1033.917 us; speedup vs baseline: 1.7634x; 1.7634x over previous
//
#include <hip/hip_runtime.h>

#define NN 100000
#define HD 64

__global__ void deg_kernel(const int* __restrict__ dst, int* __restrict__ deg, int E) {
    int e = blockIdx.x * blockDim.x + threadIdx.x;
    if (e < E) atomicAdd(&deg[dst[e]], 1);
}

__global__ void dinv_kernel(const int* __restrict__ deg, float* __restrict__ dinv, int n) {
    int v = blockIdx.x * blockDim.x + threadIdx.x;
    if (v < n) dinv[v] = rsqrtf((float)deg[v] + 1.0f);  // +1 = self loop
}

// single-block exclusive scan over deg -> row_ptr (and cursor copy)
__global__ void scan_kernel(const int* __restrict__ deg, int* __restrict__ row_ptr,
                            int* __restrict__ cursor, int n) {
    __shared__ int part[1024];
    int tid = threadIdx.x;
    int chunk = (n + 1023) / 1024;
    int start = tid * chunk;
    int end = min(start + chunk, n);
    int s = 0;
    for (int i = start; i < end; ++i) s += deg[i];
    part[tid] = s;
    __syncthreads();
    for (int off = 1; off < 1024; off <<= 1) {
        int v = (tid >= off) ? part[tid - off] : 0;
        __syncthreads();
        part[tid] += v;
        __syncthreads();
    }
    int run = (tid == 0) ? 0 : part[tid - 1];
    for (int i = start; i < end; ++i) {
        row_ptr[i] = run;
        cursor[i] = run;
        run += deg[i];
    }
    if (tid == 1023) row_ptr[n] = run;
}

__global__ void fill_kernel(const int* __restrict__ src, const int* __restrict__ dst,
                            int* __restrict__ cursor, int* __restrict__ csr_src, int E) {
    int e = blockIdx.x * blockDim.x + threadIdx.x;
    if (e < E) {
        int pos = atomicAdd(&cursor[dst[e]], 1);
        csr_src[pos] = src[e];
    }
}

// H = (X @ W) * dinv[row]  (X: [n,64], W: [64,64]) — 16 rows per block
__global__ void matmul64_kernel(const float* __restrict__ X, const float* __restrict__ W,
                                const float* __restrict__ dinv, float* __restrict__ H) {
    __shared__ float Wl[64 * 64];
    __shared__ float Xs[16 * 64];
    int tid = threadIdx.x;
#pragma unroll
    for (int i = 0; i < 16; ++i) Wl[tid + 256 * i] = W[tid + 256 * i];
    int row0 = blockIdx.x * 16;
#pragma unroll
    for (int i = 0; i < 4; ++i) Xs[tid + 256 * i] = X[row0 * 64 + tid + 256 * i];
    __syncthreads();
    int c = tid & 63, rq = tid >> 6;
    float acc[4] = {0.f, 0.f, 0.f, 0.f};
    for (int k = 0; k < 64; ++k) {
        float w = Wl[k * 64 + c];
#pragma unroll
        for (int j = 0; j < 4; ++j) acc[j] += Xs[(rq * 4 + j) * 64 + k] * w;
    }
#pragma unroll
    for (int j = 0; j < 4; ++j) {
        int row = row0 + rq * 4 + j;
        H[(size_t)row * HD + c] = acc[j] * dinv[row];
    }
}

// one wave per node: acc = h'[v] + sum_{s in in(v)} h'[s]; out = relu(acc*dinv[v]+b[+res])
__global__ void agg_kernel(const float* __restrict__ h, const int* __restrict__ row_ptr,
                           const int* __restrict__ csr_src, const float* __restrict__ dinv,
                           const float* __restrict__ b, const float* __restrict__ xprev,
                           float* __restrict__ xout, int n, int residual) {
    int lane = threadIdx.x & 63;
    int node = (blockIdx.x * blockDim.x + threadIdx.x) >> 6;
    if (node >= n) return;
    int beg = row_ptr[node], end = row_ptr[node + 1];
    float acc = h[(size_t)node * HD + lane];  // self loop (h pre-scaled by dinv)
    for (int j = beg; j < end; j += 64) {
        int cnt = min(64, end - j);
        int sv = (lane < cnt) ? csr_src[j + lane] : 0;
        for (int i = 0; i < cnt; ++i) {
            int s = __shfl(sv, i);
            acc += h[(size_t)s * HD + lane];
        }
    }
    float v = acc * dinv[node] + b[lane];
    if (residual) v += xprev[(size_t)node * HD + lane];
    xout[(size_t)node * HD + lane] = fmaxf(v, 0.0f);
}

// one wave per node: 3 dot products of length 64 via shuffle reduce
__global__ void final_kernel(const float* __restrict__ xc, const float* __restrict__ Wc,
                             const float* __restrict__ bc, float* __restrict__ out, int n) {
    int tid = threadIdx.x;
    int lane = tid & 63;
    int w = tid >> 6;
    int node = blockIdx.x * 4 + w;
    if (node >= n) return;
    float xv = xc[(size_t)node * HD + lane];
#pragma unroll
    for (int j = 0; j < 3; ++j) {
        float p = xv * Wc[lane * 3 + j];
#pragma unroll
        for (int off = 32; off > 0; off >>= 1) p += __shfl_down(p, off);
        if (lane == 0) out[node * 3 + j] = p + bc[j];
    }
}

extern "C" void kernel_launch(void* const* d_in, const int* in_sizes, int n_in,
                              void* d_out, int out_size, void* d_ws, size_t ws_size,
                              hipStream_t stream) {
    const float* x  = (const float*)d_in[0];
    const int*   ei = (const int*)d_in[1];
    const float* Ws = (const float*)d_in[2];
    const float* bs = (const float*)d_in[3];
    const float* Wc = (const float*)d_in[4];
    const float* bc = (const float*)d_in[5];
    float* out = (float*)d_out;

    int E = in_sizes[1] / 2;
    const int* src = ei;
    const int* dst = ei + E;

    // workspace layout (all offsets in elements, 4-byte)
    char* wsb = (char*)d_ws;
    size_t off = 0;
    int*   deg     = (int*)(wsb + off); off += 100352 * 4;
    float* dinv    = (float*)(wsb + off); off += 100352 * 4;
    int*   row_ptr = (int*)(wsb + off); off += 100608 * 4;
    int*   cursor  = (int*)(wsb + off); off += 100352 * 4;
    int*   csr_src = (int*)(wsb + off); off += ((size_t)E + 256) * 4;
    float* h       = (float*)(wsb + off); off += (size_t)NN * HD * 4;
    float* xa      = (float*)(wsb + off); off += (size_t)NN * HD * 4;
    float* xb      = (float*)(wsb + off); off += (size_t)NN * HD * 4;

    // graph build
    hipMemsetAsync(deg, 0, NN * sizeof(int), stream);
    deg_kernel<<<(E + 255) / 256, 256, 0, stream>>>(dst, deg, E);
    dinv_kernel<<<(NN + 255) / 256, 256, 0, stream>>>(deg, dinv, NN);
    scan_kernel<<<1, 1024, 0, stream>>>(deg, row_ptr, cursor, NN);
    fill_kernel<<<(E + 255) / 256, 256, 0, stream>>>(src, dst, cursor, csr_src, E);

    // layers (ping-pong xa/xb)
    const float* xin = x;
    float* bufs[2] = {xa, xb};
    for (int l = 0; l < 4; ++l) {
        float* xout = bufs[l & 1];
        matmul64_kernel<<<NN / 16, 256, 0, stream>>>(xin, Ws + (size_t)l * HD * HD, dinv, h);
        agg_kernel<<<(NN * 64 + 255) / 256, 256, 0, stream>>>(
            h, row_ptr, csr_src, dinv, bs + l * HD, xin, xout, NN, l > 0);
        xin = xout;
    }
    final_kernel<<<(NN + 3) / 4, 256, 0, stream>>>(bufs[1], Wc, bc, out, NN);
}

// Round 3
// 658.377 us; speedup vs baseline: 2.7693x; 1.5704x over previous
//
#include <hip/hip_runtime.h>

#define NN 100000
#define HD 64

__global__ void deg_kernel(const int* __restrict__ dst, int* __restrict__ deg, int E) {
    int e = blockIdx.x * blockDim.x + threadIdx.x;
    if (e < E) atomicAdd(&deg[dst[e]], 1);
}

__global__ void dinv_kernel(const int* __restrict__ deg, float* __restrict__ dinv, int n) {
    int v = blockIdx.x * blockDim.x + threadIdx.x;
    if (v < n) dinv[v] = rsqrtf((float)deg[v] + 1.0f);  // +1 = self loop
}

// ---- 3-kernel exclusive scan over deg -> row_ptr, cursor ----
__global__ void scanA_kernel(const int* __restrict__ deg, int* __restrict__ bsum, int n) {
    __shared__ int sm[256];
    int i = blockIdx.x * 256 + threadIdx.x;
    sm[threadIdx.x] = (i < n) ? deg[i] : 0;
    __syncthreads();
    for (int off = 128; off > 0; off >>= 1) {
        if (threadIdx.x < off) sm[threadIdx.x] += sm[threadIdx.x + off];
        __syncthreads();
    }
    if (threadIdx.x == 0) bsum[blockIdx.x] = sm[0];
}

// single block, 512 threads: exclusive-scan nb (<512) block sums; write row_ptr[n]=total
__global__ void scanB_kernel(int* __restrict__ bsum, int* __restrict__ row_ptr, int nb, int n) {
    __shared__ int sm[512];
    int t = threadIdx.x;
    int v = (t < nb) ? bsum[t] : 0;
    sm[t] = v;
    __syncthreads();
    for (int off = 1; off < 512; off <<= 1) {
        int u = (t >= off) ? sm[t - off] : 0;
        __syncthreads();
        sm[t] += u;
        __syncthreads();
    }
    if (t < nb) bsum[t] = sm[t] - v;  // exclusive block offset
    if (t == 511) row_ptr[n] = sm[511];
}

__global__ void scanC_kernel(const int* __restrict__ deg, const int* __restrict__ bsum,
                             int* __restrict__ row_ptr, int* __restrict__ cursor, int n) {
    __shared__ int sm[256];
    int i = blockIdx.x * 256 + threadIdx.x;
    int v = (i < n) ? deg[i] : 0;
    sm[threadIdx.x] = v;
    __syncthreads();
    for (int off = 1; off < 256; off <<= 1) {
        int u = (threadIdx.x >= off) ? sm[threadIdx.x - off] : 0;
        __syncthreads();
        sm[threadIdx.x] += u;
        __syncthreads();
    }
    if (i < n) {
        int excl = sm[threadIdx.x] - v + bsum[blockIdx.x];
        row_ptr[i] = excl;
        cursor[i] = excl;
    }
}

__global__ void fill_kernel(const int* __restrict__ src, const int* __restrict__ dst,
                            int* __restrict__ cursor, int* __restrict__ csr_src, int E) {
    int e = blockIdx.x * blockDim.x + threadIdx.x;
    if (e < E) {
        int pos = atomicAdd(&cursor[dst[e]], 1);
        csr_src[pos] = src[e];
    }
}

// H = (X @ W) * dinv[row]  (X: [n,64], W: [64,64]) — 16 rows per block
__global__ void matmul64_kernel(const float* __restrict__ X, const float* __restrict__ W,
                                const float* __restrict__ dinv, float* __restrict__ H) {
    __shared__ float Wl[64 * 64];
    __shared__ float Xs[16 * 64];
    int tid = threadIdx.x;
#pragma unroll
    for (int i = 0; i < 16; ++i) Wl[tid + 256 * i] = W[tid + 256 * i];
    int row0 = blockIdx.x * 16;
#pragma unroll
    for (int i = 0; i < 4; ++i) Xs[tid + 256 * i] = X[row0 * 64 + tid + 256 * i];
    __syncthreads();
    int c = tid & 63, rq = tid >> 6;
    float acc[4] = {0.f, 0.f, 0.f, 0.f};
    for (int k = 0; k < 64; ++k) {
        float w = Wl[k * 64 + c];
#pragma unroll
        for (int j = 0; j < 4; ++j) acc[j] += Xs[(rq * 4 + j) * 64 + k] * w;
    }
#pragma unroll
    for (int j = 0; j < 4; ++j) {
        int row = row0 + rq * 4 + j;
        H[(size_t)row * HD + c] = acc[j] * dinv[row];
    }
}

// one wave per node; lane = (quarter q, float4-slot c4); 4 edges per inner iter
__global__ void agg_kernel(const float4* __restrict__ h4, const int* __restrict__ row_ptr,
                           const int* __restrict__ csr_src, const float* __restrict__ dinv,
                           const float* __restrict__ b, const float* __restrict__ xprev,
                           float* __restrict__ xout, int n, int residual) {
    int lane = threadIdx.x & 63;
    int node = (blockIdx.x * blockDim.x + threadIdx.x) >> 6;
    if (node >= n) return;
    int q = lane >> 4;
    int c4 = lane & 15;
    int beg = row_ptr[node], end = row_ptr[node + 1];
    float4 acc = make_float4(0.f, 0.f, 0.f, 0.f);
    for (int j = beg; j < end; j += 64) {
        int cnt = min(64, end - j);
        int sv = (lane < cnt) ? csr_src[j + lane] : 0;
        for (int i = 0; i < cnt; i += 4) {
            int e = i + q;
            int s = __shfl(sv, e);
            if (e < cnt) {
                float4 hv = h4[(size_t)s * 16 + c4];
                acc.x += hv.x; acc.y += hv.y; acc.z += hv.z; acc.w += hv.w;
            }
        }
    }
    if (q == 0) {  // self loop (h pre-scaled by dinv[src])
        float4 hv = h4[(size_t)node * 16 + c4];
        acc.x += hv.x; acc.y += hv.y; acc.z += hv.z; acc.w += hv.w;
    }
#pragma unroll
    for (int off = 16; off < 64; off <<= 1) {
        acc.x += __shfl_down(acc.x, off);
        acc.y += __shfl_down(acc.y, off);
        acc.z += __shfl_down(acc.z, off);
        acc.w += __shfl_down(acc.w, off);
    }
    if (lane < 16) {
        float dn = dinv[node];
        const float4* b4 = (const float4*)b;
        float4 bb = b4[c4];
        float4 v;
        v.x = acc.x * dn + bb.x; v.y = acc.y * dn + bb.y;
        v.z = acc.z * dn + bb.z; v.w = acc.w * dn + bb.w;
        if (residual) {
            float4 r = ((const float4*)xprev)[(size_t)node * 16 + c4];
            v.x += r.x; v.y += r.y; v.z += r.z; v.w += r.w;
        }
        v.x = fmaxf(v.x, 0.f); v.y = fmaxf(v.y, 0.f);
        v.z = fmaxf(v.z, 0.f); v.w = fmaxf(v.w, 0.f);
        ((float4*)xout)[(size_t)node * 16 + c4] = v;
    }
}

// one wave per node: 3 dot products of length 64 via shuffle reduce
__global__ void final_kernel(const float* __restrict__ xc, const float* __restrict__ Wc,
                             const float* __restrict__ bc, float* __restrict__ out, int n) {
    int tid = threadIdx.x;
    int lane = tid & 63;
    int w = tid >> 6;
    int node = blockIdx.x * 4 + w;
    if (node >= n) return;
    float xv = xc[(size_t)node * HD + lane];
#pragma unroll
    for (int j = 0; j < 3; ++j) {
        float p = xv * Wc[lane * 3 + j];
#pragma unroll
        for (int off = 32; off > 0; off >>= 1) p += __shfl_down(p, off);
        if (lane == 0) out[node * 3 + j] = p + bc[j];
    }
}

extern "C" void kernel_launch(void* const* d_in, const int* in_sizes, int n_in,
                              void* d_out, int out_size, void* d_ws, size_t ws_size,
                              hipStream_t stream) {
    const float* x  = (const float*)d_in[0];
    const int*   ei = (const int*)d_in[1];
    const float* Ws = (const float*)d_in[2];
    const float* bs = (const float*)d_in[3];
    const float* Wc = (const float*)d_in[4];
    const float* bc = (const float*)d_in[5];
    float* out = (float*)d_out;

    int E = in_sizes[1] / 2;
    const int* src = ei;
    const int* dst = ei + E;
    int nb = (NN + 255) / 256;

    char* wsb = (char*)d_ws;
    size_t off = 0;
    int*   deg     = (int*)(wsb + off); off += 100352 * 4;
    float* dinv    = (float*)(wsb + off); off += 100352 * 4;
    int*   row_ptr = (int*)(wsb + off); off += 100608 * 4;
    int*   cursor  = (int*)(wsb + off); off += 100352 * 4;
    int*   bsum    = (int*)(wsb + off); off += 512 * 4;
    int*   csr_src = (int*)(wsb + off); off += ((size_t)E + 256) * 4;
    float* h       = (float*)(wsb + off); off += (size_t)NN * HD * 4;
    float* xa      = (float*)(wsb + off); off += (size_t)NN * HD * 4;
    float* xb      = (float*)(wsb + off); off += (size_t)NN * HD * 4;

    // graph build
    hipMemsetAsync(deg, 0, NN * sizeof(int), stream);
    deg_kernel<<<(E + 255) / 256, 256, 0, stream>>>(dst, deg, E);
    dinv_kernel<<<(NN + 255) / 256, 256, 0, stream>>>(deg, dinv, NN);
    scanA_kernel<<<nb, 256, 0, stream>>>(deg, bsum, NN);
    scanB_kernel<<<1, 512, 0, stream>>>(bsum, row_ptr, nb, NN);
    scanC_kernel<<<nb, 256, 0, stream>>>(deg, bsum, row_ptr, cursor, NN);
    fill_kernel<<<(E + 255) / 256, 256, 0, stream>>>(src, dst, cursor, csr_src, E);

    // layers (ping-pong xa/xb)
    const float* xin = x;
    float* bufs[2] = {xa, xb};
    for (int l = 0; l < 4; ++l) {
        float* xout = bufs[l & 1];
        matmul64_kernel<<<NN / 16, 256, 0, stream>>>(xin, Ws + (size_t)l * HD * HD, dinv, h);
        agg_kernel<<<(NN * 64 + 255) / 256, 256, 0, stream>>>(
            (const float4*)h, row_ptr, csr_src, dinv, bs + l * HD, xin, xout, NN, l > 0);
        xin = xout;
    }
    final_kernel<<<(NN + 3) / 4, 256, 0, stream>>>(bufs[1], Wc, bc, out, NN);
}

// Round 4
// 613.959 us; speedup vs baseline: 2.9696x; 1.0723x over previous
//
#include <hip/hip_runtime.h>

#define NN 100000
#define HD 64

__global__ void deg_kernel(const int* __restrict__ dst, int* __restrict__ deg, int E) {
    int e = blockIdx.x * blockDim.x + threadIdx.x;
    if (e < E) atomicAdd(&deg[dst[e]], 1);
}

__global__ void dinv_kernel(const int* __restrict__ deg, float* __restrict__ dinv, int n) {
    int v = blockIdx.x * blockDim.x + threadIdx.x;
    if (v < n) dinv[v] = rsqrtf((float)deg[v] + 1.0f);  // +1 = self loop
}

// ---- 3-kernel exclusive scan over deg -> row_ptr, cursor ----
__global__ void scanA_kernel(const int* __restrict__ deg, int* __restrict__ bsum, int n) {
    __shared__ int sm[256];
    int i = blockIdx.x * 256 + threadIdx.x;
    sm[threadIdx.x] = (i < n) ? deg[i] : 0;
    __syncthreads();
    for (int off = 128; off > 0; off >>= 1) {
        if (threadIdx.x < off) sm[threadIdx.x] += sm[threadIdx.x + off];
        __syncthreads();
    }
    if (threadIdx.x == 0) bsum[blockIdx.x] = sm[0];
}

__global__ void scanB_kernel(int* __restrict__ bsum, int* __restrict__ row_ptr, int nb, int n) {
    __shared__ int sm[512];
    int t = threadIdx.x;
    int v = (t < nb) ? bsum[t] : 0;
    sm[t] = v;
    __syncthreads();
    for (int off = 1; off < 512; off <<= 1) {
        int u = (t >= off) ? sm[t - off] : 0;
        __syncthreads();
        sm[t] += u;
        __syncthreads();
    }
    if (t < nb) bsum[t] = sm[t] - v;  // exclusive block offset
    if (t == 511) row_ptr[n] = sm[511];
}

__global__ void scanC_kernel(const int* __restrict__ deg, const int* __restrict__ bsum,
                             int* __restrict__ row_ptr, int* __restrict__ cursor, int n) {
    __shared__ int sm[256];
    int i = blockIdx.x * 256 + threadIdx.x;
    int v = (i < n) ? deg[i] : 0;
    sm[threadIdx.x] = v;
    __syncthreads();
    for (int off = 1; off < 256; off <<= 1) {
        int u = (threadIdx.x >= off) ? sm[threadIdx.x - off] : 0;
        __syncthreads();
        sm[threadIdx.x] += u;
        __syncthreads();
    }
    if (i < n) {
        int excl = sm[threadIdx.x] - v + bsum[blockIdx.x];
        row_ptr[i] = excl;
        cursor[i] = excl;
    }
}

__global__ void fill_kernel(const int* __restrict__ src, const int* __restrict__ dst,
                            int* __restrict__ cursor, int* __restrict__ csr_src, int E) {
    int e = blockIdx.x * blockDim.x + threadIdx.x;
    if (e < E) {
        int pos = atomicAdd(&cursor[dst[e]], 1);
        csr_src[pos] = src[e];
    }
}

// H = (X @ W) * dinv[row] — 64x64 tile/block, 4x4 micro-tile/thread
__global__ __launch_bounds__(256) void matmul64_kernel(const float* __restrict__ X,
                                                       const float* __restrict__ W,
                                                       const float* __restrict__ dinv,
                                                       float* __restrict__ H, int n) {
    __shared__ float Wl[64 * 64];      // [k][c], float4-aligned
    __shared__ float Xs[64 * 65];      // [r][k], padded
    int tid = threadIdx.x;
    int row0 = blockIdx.x * 64;
    const float4* W4 = (const float4*)W;
    float4* Wl4 = (float4*)Wl;
#pragma unroll
    for (int i = 0; i < 4; ++i) Wl4[tid + 256 * i] = W4[tid + 256 * i];
#pragma unroll
    for (int i = 0; i < 4; ++i) {
        int l = tid + 256 * i;          // 1024 float4s = 64 rows x 16
        int r = l >> 4, k0 = (l & 15) * 4;
        int row = row0 + r;
        float4 xv = (row < n) ? ((const float4*)X)[(size_t)row * 16 + (l & 15)]
                              : make_float4(0.f, 0.f, 0.f, 0.f);
        Xs[r * 65 + k0 + 0] = xv.x;
        Xs[r * 65 + k0 + 1] = xv.y;
        Xs[r * 65 + k0 + 2] = xv.z;
        Xs[r * 65 + k0 + 3] = xv.w;
    }
    __syncthreads();
    int tx = tid & 15, ty = tid >> 4;   // cols c0=4*tx, rows r0=4*ty
    float acc[4][4] = {};
    const float4* Wlr4 = (const float4*)Wl;
#pragma unroll 4
    for (int k = 0; k < 64; ++k) {
        float4 b = Wlr4[k * 16 + tx];
        float a0 = Xs[(ty * 4 + 0) * 65 + k];
        float a1 = Xs[(ty * 4 + 1) * 65 + k];
        float a2 = Xs[(ty * 4 + 2) * 65 + k];
        float a3 = Xs[(ty * 4 + 3) * 65 + k];
        acc[0][0] += a0 * b.x; acc[0][1] += a0 * b.y; acc[0][2] += a0 * b.z; acc[0][3] += a0 * b.w;
        acc[1][0] += a1 * b.x; acc[1][1] += a1 * b.y; acc[1][2] += a1 * b.z; acc[1][3] += a1 * b.w;
        acc[2][0] += a2 * b.x; acc[2][1] += a2 * b.y; acc[2][2] += a2 * b.z; acc[2][3] += a2 * b.w;
        acc[3][0] += a3 * b.x; acc[3][1] += a3 * b.y; acc[3][2] += a3 * b.z; acc[3][3] += a3 * b.w;
    }
#pragma unroll
    for (int j = 0; j < 4; ++j) {
        int row = row0 + ty * 4 + j;
        if (row < n) {
            float dn = dinv[row];
            float4 o = make_float4(acc[j][0] * dn, acc[j][1] * dn, acc[j][2] * dn, acc[j][3] * dn);
            ((float4*)H)[(size_t)row * 16 + tx] = o;
        }
    }
}

// one QUARTER-wave (16 lanes) per node; lane c4 owns channels 4*c4..4*c4+3 as float4.
// Epilogue: bias + residual + relu; layer 3 fuses the 64->3 projection.
__global__ void agg_kernel(const float4* __restrict__ h4, const int* __restrict__ row_ptr,
                           const int* __restrict__ csr_src, const float* __restrict__ dinv,
                           const float* __restrict__ b, const float* __restrict__ xprev,
                           float* __restrict__ xout, float* __restrict__ outp,
                           const float* __restrict__ Wc, const float* __restrict__ bc,
                           int n, int residual, int project) {
    int lane = threadIdx.x & 63;
    int q = lane >> 4, c4 = lane & 15;
    int wid = (blockIdx.x * blockDim.x + threadIdx.x) >> 6;
    int node = wid * 4 + q;
    bool active = node < n;
    int nc = active ? node : 0;
    int beg = row_ptr[nc], end = row_ptr[nc + 1];
    int cnt = end - beg;
    float4 acc = h4[(size_t)nc * 16 + c4];  // self loop (h pre-scaled by dinv[src])
    for (int k = 0; k < cnt; k += 16) {
        int p = beg + k + c4;
        int sv = (p < end) ? csr_src[p] : 0;
        int m = min(16, cnt - k);
        for (int i = 0; i < m; ++i) {
            int s = __shfl(sv, q * 16 + i);
            float4 hv = h4[(size_t)s * 16 + c4];
            acc.x += hv.x; acc.y += hv.y; acc.z += hv.z; acc.w += hv.w;
        }
    }
    if (active) {
        float dn = dinv[node];
        float4 bb = ((const float4*)b)[c4];
        float4 v;
        v.x = acc.x * dn + bb.x; v.y = acc.y * dn + bb.y;
        v.z = acc.z * dn + bb.z; v.w = acc.w * dn + bb.w;
        if (residual) {
            float4 r = ((const float4*)xprev)[(size_t)node * 16 + c4];
            v.x += r.x; v.y += r.y; v.z += r.z; v.w += r.w;
        }
        v.x = fmaxf(v.x, 0.f); v.y = fmaxf(v.y, 0.f);
        v.z = fmaxf(v.z, 0.f); v.w = fmaxf(v.w, 0.f);
        if (!project) {
            ((float4*)xout)[(size_t)node * 16 + c4] = v;
        } else {
            int cb = c4 * 4;
#pragma unroll
            for (int j = 0; j < 3; ++j) {
                float p = v.x * Wc[(cb + 0) * 3 + j] + v.y * Wc[(cb + 1) * 3 + j] +
                          v.z * Wc[(cb + 2) * 3 + j] + v.w * Wc[(cb + 3) * 3 + j];
                p += __shfl_down(p, 8);
                p += __shfl_down(p, 4);
                p += __shfl_down(p, 2);
                p += __shfl_down(p, 1);
                if (c4 == 0) outp[node * 3 + j] = p + bc[j];
            }
        }
    }
}

extern "C" void kernel_launch(void* const* d_in, const int* in_sizes, int n_in,
                              void* d_out, int out_size, void* d_ws, size_t ws_size,
                              hipStream_t stream) {
    const float* x  = (const float*)d_in[0];
    const int*   ei = (const int*)d_in[1];
    const float* Ws = (const float*)d_in[2];
    const float* bs = (const float*)d_in[3];
    const float* Wc = (const float*)d_in[4];
    const float* bc = (const float*)d_in[5];
    float* out = (float*)d_out;

    int E = in_sizes[1] / 2;
    const int* src = ei;
    const int* dst = ei + E;
    int nb = (NN + 255) / 256;

    char* wsb = (char*)d_ws;
    size_t off = 0;
    int*   deg     = (int*)(wsb + off); off += 100352 * 4;
    float* dinv    = (float*)(wsb + off); off += 100352 * 4;
    int*   row_ptr = (int*)(wsb + off); off += 100608 * 4;
    int*   cursor  = (int*)(wsb + off); off += 100352 * 4;
    int*   bsum    = (int*)(wsb + off); off += 512 * 4;
    int*   csr_src = (int*)(wsb + off); off += ((size_t)E + 256) * 4;
    float* h       = (float*)(wsb + off); off += (size_t)NN * HD * 4;
    float* xa      = (float*)(wsb + off); off += (size_t)NN * HD * 4;
    float* xb      = (float*)(wsb + off); off += (size_t)NN * HD * 4;

    // graph build
    hipMemsetAsync(deg, 0, NN * sizeof(int), stream);
    deg_kernel<<<(E + 255) / 256, 256, 0, stream>>>(dst, deg, E);
    dinv_kernel<<<(NN + 255) / 256, 256, 0, stream>>>(deg, dinv, NN);
    scanA_kernel<<<nb, 256, 0, stream>>>(deg, bsum, NN);
    scanB_kernel<<<1, 512, 0, stream>>>(bsum, row_ptr, nb, NN);
    scanC_kernel<<<nb, 256, 0, stream>>>(deg, bsum, row_ptr, cursor, NN);
    fill_kernel<<<(E + 255) / 256, 256, 0, stream>>>(src, dst, cursor, csr_src, E);

    // layers (ping-pong xa/xb); layer 3 fuses projection into agg epilogue
    const float* xin = x;
    float* bufs[2] = {xa, xb};
    int agg_blocks = ((NN + 3) / 4 * 64 + 255) / 256;  // 4 nodes per wave
    for (int l = 0; l < 4; ++l) {
        float* xout = bufs[l & 1];
        matmul64_kernel<<<(NN + 63) / 64, 256, 0, stream>>>(
            xin, Ws + (size_t)l * HD * HD, dinv, h, NN);
        agg_kernel<<<agg_blocks, 256, 0, stream>>>(
            (const float4*)h, row_ptr, csr_src, dinv, bs + l * HD, xin, xout,
            out, Wc, bc, NN, l > 0, l == 3);
        xin = xout;
    }
}

// Round 5
// 587.962 us; speedup vs baseline: 3.1009x; 1.0442x over previous
//
#include <hip/hip_runtime.h>

#define NN 100000
#define HD 64

__global__ void deg_kernel(const int* __restrict__ dst, int* __restrict__ deg, int E) {
    int e = blockIdx.x * blockDim.x + threadIdx.x;
    if (e < E) atomicAdd(&deg[dst[e]], 1);
}

__global__ void dinv_kernel(const int* __restrict__ deg, float* __restrict__ dinv, int n) {
    int v = blockIdx.x * blockDim.x + threadIdx.x;
    if (v < n) dinv[v] = rsqrtf((float)deg[v] + 1.0f);  // +1 = self loop
}

// ---- 3-kernel exclusive scan over deg -> row_ptr, cursor ----
__global__ void scanA_kernel(const int* __restrict__ deg, int* __restrict__ bsum, int n) {
    __shared__ int sm[256];
    int i = blockIdx.x * 256 + threadIdx.x;
    sm[threadIdx.x] = (i < n) ? deg[i] : 0;
    __syncthreads();
    for (int off = 128; off > 0; off >>= 1) {
        if (threadIdx.x < off) sm[threadIdx.x] += sm[threadIdx.x + off];
        __syncthreads();
    }
    if (threadIdx.x == 0) bsum[blockIdx.x] = sm[0];
}

__global__ void scanB_kernel(int* __restrict__ bsum, int* __restrict__ row_ptr, int nb, int n) {
    __shared__ int sm[512];
    int t = threadIdx.x;
    int v = (t < nb) ? bsum[t] : 0;
    sm[t] = v;
    __syncthreads();
    for (int off = 1; off < 512; off <<= 1) {
        int u = (t >= off) ? sm[t - off] : 0;
        __syncthreads();
        sm[t] += u;
        __syncthreads();
    }
    if (t < nb) bsum[t] = sm[t] - v;  // exclusive block offset
    if (t == 511) row_ptr[n] = sm[511];
}

__global__ void scanC_kernel(const int* __restrict__ deg, const int* __restrict__ bsum,
                             int* __restrict__ row_ptr, int* __restrict__ cursor, int n) {
    __shared__ int sm[256];
    int i = blockIdx.x * 256 + threadIdx.x;
    int v = (i < n) ? deg[i] : 0;
    sm[threadIdx.x] = v;
    __syncthreads();
    for (int off = 1; off < 256; off <<= 1) {
        int u = (threadIdx.x >= off) ? sm[threadIdx.x - off] : 0;
        __syncthreads();
        sm[threadIdx.x] += u;
        __syncthreads();
    }
    if (i < n) {
        int excl = sm[threadIdx.x] - v + bsum[blockIdx.x];
        row_ptr[i] = excl;
        cursor[i] = excl;
    }
}

__global__ void fill_kernel(const int* __restrict__ src, const int* __restrict__ dst,
                            int* __restrict__ cursor, int* __restrict__ csr_src, int E) {
    int e = blockIdx.x * blockDim.x + threadIdx.x;
    if (e < E) {
        int pos = atomicAdd(&cursor[dst[e]], 1);
        csr_src[pos] = src[e];
    }
}

// H = (X @ W) * dinv[row] — 64x64 tile/block, 4x4 micro-tile/thread
__global__ __launch_bounds__(256) void matmul64_kernel(const float* __restrict__ X,
                                                       const float* __restrict__ W,
                                                       const float* __restrict__ dinv,
                                                       float* __restrict__ H, int n) {
    __shared__ float Wl[64 * 64];      // [k][c], float4-aligned
    __shared__ float Xs[64 * 65];      // [r][k], padded
    int tid = threadIdx.x;
    int row0 = blockIdx.x * 64;
    const float4* W4 = (const float4*)W;
    float4* Wl4 = (float4*)Wl;
#pragma unroll
    for (int i = 0; i < 4; ++i) Wl4[tid + 256 * i] = W4[tid + 256 * i];
#pragma unroll
    for (int i = 0; i < 4; ++i) {
        int l = tid + 256 * i;          // 1024 float4s = 64 rows x 16
        int r = l >> 4, k0 = (l & 15) * 4;
        int row = row0 + r;
        float4 xv = (row < n) ? ((const float4*)X)[(size_t)row * 16 + (l & 15)]
                              : make_float4(0.f, 0.f, 0.f, 0.f);
        Xs[r * 65 + k0 + 0] = xv.x;
        Xs[r * 65 + k0 + 1] = xv.y;
        Xs[r * 65 + k0 + 2] = xv.z;
        Xs[r * 65 + k0 + 3] = xv.w;
    }
    __syncthreads();
    int tx = tid & 15, ty = tid >> 4;   // cols c0=4*tx, rows r0=4*ty
    float acc[4][4] = {};
    const float4* Wlr4 = (const float4*)Wl;
#pragma unroll 4
    for (int k = 0; k < 64; ++k) {
        float4 b = Wlr4[k * 16 + tx];
        float a0 = Xs[(ty * 4 + 0) * 65 + k];
        float a1 = Xs[(ty * 4 + 1) * 65 + k];
        float a2 = Xs[(ty * 4 + 2) * 65 + k];
        float a3 = Xs[(ty * 4 + 3) * 65 + k];
        acc[0][0] += a0 * b.x; acc[0][1] += a0 * b.y; acc[0][2] += a0 * b.z; acc[0][3] += a0 * b.w;
        acc[1][0] += a1 * b.x; acc[1][1] += a1 * b.y; acc[1][2] += a1 * b.z; acc[1][3] += a1 * b.w;
        acc[2][0] += a2 * b.x; acc[2][1] += a2 * b.y; acc[2][2] += a2 * b.z; acc[2][3] += a2 * b.w;
        acc[3][0] += a3 * b.x; acc[3][1] += a3 * b.y; acc[3][2] += a3 * b.z; acc[3][3] += a3 * b.w;
    }
#pragma unroll
    for (int j = 0; j < 4; ++j) {
        int row = row0 + ty * 4 + j;
        if (row < n) {
            float dn = dinv[row];
            float4 o = make_float4(acc[j][0] * dn, acc[j][1] * dn, acc[j][2] * dn, acc[j][3] * dn);
            ((float4*)H)[(size_t)row * 16 + tx] = o;
        }
    }
}

#define ACC4(A, V) do { (A).x += (V).x; (A).y += (V).y; (A).z += (V).z; (A).w += (V).w; } while (0)

// one QUARTER-wave (16 lanes) per node; lane c4 owns channels 4*c4..4*c4+3 as float4.
// Inner edge loop unrolled 8/4/1-wide so up to 8 gathers are in flight per quarter.
__global__ void agg_kernel(const float4* __restrict__ h4, const int* __restrict__ row_ptr,
                           const int* __restrict__ csr_src, const float* __restrict__ dinv,
                           const float* __restrict__ b, const float* __restrict__ xprev,
                           float* __restrict__ xout, float* __restrict__ outp,
                           const float* __restrict__ Wc, const float* __restrict__ bc,
                           int n, int residual, int project) {
    int lane = threadIdx.x & 63;
    int q = lane >> 4, c4 = lane & 15;
    int wid = (blockIdx.x * blockDim.x + threadIdx.x) >> 6;
    int node = wid * 4 + q;
    bool active = node < n;
    int nc = active ? node : 0;
    int beg = row_ptr[nc], end = row_ptr[nc + 1];
    int cnt = end - beg;
    float4 acc = h4[(size_t)nc * 16 + c4];  // self loop (h pre-scaled by dinv[src])
    int base = q * 16;
    for (int k = 0; k < cnt; k += 16) {
        int p = beg + k + c4;
        int sv = (p < end) ? csr_src[p] : 0;
        int m = min(16, cnt - k);
        int i = 0;
        for (; i + 8 <= m; i += 8) {
            int s0 = __shfl(sv, base + i + 0);
            int s1 = __shfl(sv, base + i + 1);
            int s2 = __shfl(sv, base + i + 2);
            int s3 = __shfl(sv, base + i + 3);
            int s4 = __shfl(sv, base + i + 4);
            int s5 = __shfl(sv, base + i + 5);
            int s6 = __shfl(sv, base + i + 6);
            int s7 = __shfl(sv, base + i + 7);
            float4 v0 = h4[(size_t)s0 * 16 + c4];
            float4 v1 = h4[(size_t)s1 * 16 + c4];
            float4 v2 = h4[(size_t)s2 * 16 + c4];
            float4 v3 = h4[(size_t)s3 * 16 + c4];
            float4 v4 = h4[(size_t)s4 * 16 + c4];
            float4 v5 = h4[(size_t)s5 * 16 + c4];
            float4 v6 = h4[(size_t)s6 * 16 + c4];
            float4 v7 = h4[(size_t)s7 * 16 + c4];
            ACC4(acc, v0); ACC4(acc, v1); ACC4(acc, v2); ACC4(acc, v3);
            ACC4(acc, v4); ACC4(acc, v5); ACC4(acc, v6); ACC4(acc, v7);
        }
        for (; i + 4 <= m; i += 4) {
            int s0 = __shfl(sv, base + i + 0);
            int s1 = __shfl(sv, base + i + 1);
            int s2 = __shfl(sv, base + i + 2);
            int s3 = __shfl(sv, base + i + 3);
            float4 v0 = h4[(size_t)s0 * 16 + c4];
            float4 v1 = h4[(size_t)s1 * 16 + c4];
            float4 v2 = h4[(size_t)s2 * 16 + c4];
            float4 v3 = h4[(size_t)s3 * 16 + c4];
            ACC4(acc, v0); ACC4(acc, v1); ACC4(acc, v2); ACC4(acc, v3);
        }
        for (; i < m; ++i) {
            int s = __shfl(sv, base + i);
            float4 hv = h4[(size_t)s * 16 + c4];
            ACC4(acc, hv);
        }
    }
    if (active) {
        float dn = dinv[node];
        float4 bb = ((const float4*)b)[c4];
        float4 v;
        v.x = acc.x * dn + bb.x; v.y = acc.y * dn + bb.y;
        v.z = acc.z * dn + bb.z; v.w = acc.w * dn + bb.w;
        if (residual) {
            float4 r = ((const float4*)xprev)[(size_t)node * 16 + c4];
            v.x += r.x; v.y += r.y; v.z += r.z; v.w += r.w;
        }
        v.x = fmaxf(v.x, 0.f); v.y = fmaxf(v.y, 0.f);
        v.z = fmaxf(v.z, 0.f); v.w = fmaxf(v.w, 0.f);
        if (!project) {
            ((float4*)xout)[(size_t)node * 16 + c4] = v;
        } else {
            int cb = c4 * 4;
#pragma unroll
            for (int j = 0; j < 3; ++j) {
                float p = v.x * Wc[(cb + 0) * 3 + j] + v.y * Wc[(cb + 1) * 3 + j] +
                          v.z * Wc[(cb + 2) * 3 + j] + v.w * Wc[(cb + 3) * 3 + j];
                p += __shfl_down(p, 8);
                p += __shfl_down(p, 4);
                p += __shfl_down(p, 2);
                p += __shfl_down(p, 1);
                if (c4 == 0) outp[node * 3 + j] = p + bc[j];
            }
        }
    }
}

extern "C" void kernel_launch(void* const* d_in, const int* in_sizes, int n_in,
                              void* d_out, int out_size, void* d_ws, size_t ws_size,
                              hipStream_t stream) {
    const float* x  = (const float*)d_in[0];
    const int*   ei = (const int*)d_in[1];
    const float* Ws = (const float*)d_in[2];
    const float* bs = (const float*)d_in[3];
    const float* Wc = (const float*)d_in[4];
    const float* bc = (const float*)d_in[5];
    float* out = (float*)d_out;

    int E = in_sizes[1] / 2;
    const int* src = ei;
    const int* dst = ei + E;
    int nb = (NN + 255) / 256;

    char* wsb = (char*)d_ws;
    size_t off = 0;
    int*   deg     = (int*)(wsb + off); off += 100352 * 4;
    float* dinv    = (float*)(wsb + off); off += 100352 * 4;
    int*   row_ptr = (int*)(wsb + off); off += 100608 * 4;
    int*   cursor  = (int*)(wsb + off); off += 100352 * 4;
    int*   bsum    = (int*)(wsb + off); off += 512 * 4;
    int*   csr_src = (int*)(wsb + off); off += ((size_t)E + 256) * 4;
    float* h       = (float*)(wsb + off); off += (size_t)NN * HD * 4;
    float* xa      = (float*)(wsb + off); off += (size_t)NN * HD * 4;
    float* xb      = (float*)(wsb + off); off += (size_t)NN * HD * 4;

    // graph build
    hipMemsetAsync(deg, 0, NN * sizeof(int), stream);
    deg_kernel<<<(E + 255) / 256, 256, 0, stream>>>(dst, deg, E);
    dinv_kernel<<<(NN + 255) / 256, 256, 0, stream>>>(deg, dinv, NN);
    scanA_kernel<<<nb, 256, 0, stream>>>(deg, bsum, NN);
    scanB_kernel<<<1, 512, 0, stream>>>(bsum, row_ptr, nb, NN);
    scanC_kernel<<<nb, 256, 0, stream>>>(deg, bsum, row_ptr, cursor, NN);
    fill_kernel<<<(E + 255) / 256, 256, 0, stream>>>(src, dst, cursor, csr_src, E);

    // layers (ping-pong xa/xb); layer 3 fuses projection into agg epilogue
    const float* xin = x;
    float* bufs[2] = {xa, xb};
    int agg_blocks = ((NN + 3) / 4 * 64 + 255) / 256;  // 4 nodes per wave
    for (int l = 0; l < 4; ++l) {
        float* xout = bufs[l & 1];
        matmul64_kernel<<<(NN + 63) / 64, 256, 0, stream>>>(
            xin, Ws + (size_t)l * HD * HD, dinv, h, NN);
        agg_kernel<<<agg_blocks, 256, 0, stream>>>(
            (const float4*)h, row_ptr, csr_src, dinv, bs + l * HD, xin, xout,
            out, Wc, bc, NN, l > 0, l == 3);
        xin = xout;
    }
}

// Round 6
// 487.318 us; speedup vs baseline: 3.7414x; 1.2065x over previous
//
#include <hip/hip_runtime.h>
#include <hip/hip_fp16.h>

#define NN 100000
#define HD 64

__global__ void deg_kernel(const int* __restrict__ dst, int* __restrict__ deg, int E) {
    int e = blockIdx.x * blockDim.x + threadIdx.x;
    if (e < E) atomicAdd(&deg[dst[e]], 1);
}

__global__ void dinv_kernel(const int* __restrict__ deg, float* __restrict__ dinv, int n) {
    int v = blockIdx.x * blockDim.x + threadIdx.x;
    if (v < n) dinv[v] = rsqrtf((float)deg[v] + 1.0f);  // +1 = self loop
}

// ---- 3-kernel exclusive scan over deg -> row_ptr, cursor ----
__global__ void scanA_kernel(const int* __restrict__ deg, int* __restrict__ bsum, int n) {
    __shared__ int sm[256];
    int i = blockIdx.x * 256 + threadIdx.x;
    sm[threadIdx.x] = (i < n) ? deg[i] : 0;
    __syncthreads();
    for (int off = 128; off > 0; off >>= 1) {
        if (threadIdx.x < off) sm[threadIdx.x] += sm[threadIdx.x + off];
        __syncthreads();
    }
    if (threadIdx.x == 0) bsum[blockIdx.x] = sm[0];
}

__global__ void scanB_kernel(int* __restrict__ bsum, int* __restrict__ row_ptr, int nb, int n) {
    __shared__ int sm[512];
    int t = threadIdx.x;
    int v = (t < nb) ? bsum[t] : 0;
    sm[t] = v;
    __syncthreads();
    for (int off = 1; off < 512; off <<= 1) {
        int u = (t >= off) ? sm[t - off] : 0;
        __syncthreads();
        sm[t] += u;
        __syncthreads();
    }
    if (t < nb) bsum[t] = sm[t] - v;  // exclusive block offset
    if (t == 511) row_ptr[n] = sm[511];
}

__global__ void scanC_kernel(const int* __restrict__ deg, const int* __restrict__ bsum,
                             int* __restrict__ row_ptr, int* __restrict__ cursor, int n) {
    __shared__ int sm[256];
    int i = blockIdx.x * 256 + threadIdx.x;
    int v = (i < n) ? deg[i] : 0;
    sm[threadIdx.x] = v;
    __syncthreads();
    for (int off = 1; off < 256; off <<= 1) {
        int u = (threadIdx.x >= off) ? sm[threadIdx.x - off] : 0;
        __syncthreads();
        sm[threadIdx.x] += u;
        __syncthreads();
    }
    if (i < n) {
        int excl = sm[threadIdx.x] - v + bsum[blockIdx.x];
        row_ptr[i] = excl;
        cursor[i] = excl;
    }
}

__global__ void fill_kernel(const int* __restrict__ src, const int* __restrict__ dst,
                            int* __restrict__ cursor, int* __restrict__ csr_src, int E) {
    int e = blockIdx.x * blockDim.x + threadIdx.x;
    if (e < E) {
        int pos = atomicAdd(&cursor[dst[e]], 1);
        csr_src[pos] = src[e];
    }
}

// H(fp16) = (X @ W) * dinv[row] — 64x64 tile/block, 4x4 micro-tile/thread
__global__ __launch_bounds__(256) void matmul64_kernel(const float* __restrict__ X,
                                                       const float* __restrict__ W,
                                                       const float* __restrict__ dinv,
                                                       float2* __restrict__ H, int n) {
    __shared__ float Wl[64 * 64];      // [k][c], float4-aligned
    __shared__ float Xs[64 * 65];      // [r][k], padded
    int tid = threadIdx.x;
    int row0 = blockIdx.x * 64;
    const float4* W4 = (const float4*)W;
    float4* Wl4 = (float4*)Wl;
#pragma unroll
    for (int i = 0; i < 4; ++i) Wl4[tid + 256 * i] = W4[tid + 256 * i];
#pragma unroll
    for (int i = 0; i < 4; ++i) {
        int l = tid + 256 * i;          // 1024 float4s = 64 rows x 16
        int r = l >> 4, k0 = (l & 15) * 4;
        int row = row0 + r;
        float4 xv = (row < n) ? ((const float4*)X)[(size_t)row * 16 + (l & 15)]
                              : make_float4(0.f, 0.f, 0.f, 0.f);
        Xs[r * 65 + k0 + 0] = xv.x;
        Xs[r * 65 + k0 + 1] = xv.y;
        Xs[r * 65 + k0 + 2] = xv.z;
        Xs[r * 65 + k0 + 3] = xv.w;
    }
    __syncthreads();
    int tx = tid & 15, ty = tid >> 4;   // cols c0=4*tx, rows r0=4*ty
    float acc[4][4] = {};
    const float4* Wlr4 = (const float4*)Wl;
#pragma unroll 4
    for (int k = 0; k < 64; ++k) {
        float4 b = Wlr4[k * 16 + tx];
        float a0 = Xs[(ty * 4 + 0) * 65 + k];
        float a1 = Xs[(ty * 4 + 1) * 65 + k];
        float a2 = Xs[(ty * 4 + 2) * 65 + k];
        float a3 = Xs[(ty * 4 + 3) * 65 + k];
        acc[0][0] += a0 * b.x; acc[0][1] += a0 * b.y; acc[0][2] += a0 * b.z; acc[0][3] += a0 * b.w;
        acc[1][0] += a1 * b.x; acc[1][1] += a1 * b.y; acc[1][2] += a1 * b.z; acc[1][3] += a1 * b.w;
        acc[2][0] += a2 * b.x; acc[2][1] += a2 * b.y; acc[2][2] += a2 * b.z; acc[2][3] += a2 * b.w;
        acc[3][0] += a3 * b.x; acc[3][1] += a3 * b.y; acc[3][2] += a3 * b.z; acc[3][3] += a3 * b.w;
    }
#pragma unroll
    for (int j = 0; j < 4; ++j) {
        int row = row0 + ty * 4 + j;
        if (row < n) {
            float dn = dinv[row];
            __half2 p01 = __float22half2_rn(make_float2(acc[j][0] * dn, acc[j][1] * dn));
            __half2 p23 = __float22half2_rn(make_float2(acc[j][2] * dn, acc[j][3] * dn));
            float2 st;
            st.x = *reinterpret_cast<float*>(&p01);
            st.y = *reinterpret_cast<float*>(&p23);
            H[(size_t)row * 16 + tx] = st;
        }
    }
}

#define UNPACK_ACC(A, RAW) do {                                              \
    __half2 _h01 = *reinterpret_cast<__half2*>(&(RAW).x);                    \
    __half2 _h23 = *reinterpret_cast<__half2*>(&(RAW).y);                    \
    float2 _f01 = __half22float2(_h01);                                      \
    float2 _f23 = __half22float2(_h23);                                      \
    (A).x += _f01.x; (A).y += _f01.y; (A).z += _f23.x; (A).w += _f23.y;      \
} while (0)

// one QUARTER-wave (16 lanes) per node; lane c4 owns channels 4*c4..4*c4+3 (fp16 x4 = 8B).
// Inner edge loop unrolled 8/4/1-wide so up to 8 gathers are in flight per quarter.
__global__ void agg_kernel(const float2* __restrict__ h2, const int* __restrict__ row_ptr,
                           const int* __restrict__ csr_src, const float* __restrict__ dinv,
                           const float* __restrict__ b, const float* __restrict__ xprev,
                           float* __restrict__ xout, float* __restrict__ outp,
                           const float* __restrict__ Wc, const float* __restrict__ bc,
                           int n, int residual, int project) {
    int lane = threadIdx.x & 63;
    int q = lane >> 4, c4 = lane & 15;
    int wid = (blockIdx.x * blockDim.x + threadIdx.x) >> 6;
    int node = wid * 4 + q;
    bool active = node < n;
    int nc = active ? node : 0;
    int beg = row_ptr[nc], end = row_ptr[nc + 1];
    int cnt = end - beg;
    float4 acc = make_float4(0.f, 0.f, 0.f, 0.f);
    {
        float2 raw = h2[(size_t)nc * 16 + c4];  // self loop (pre-scaled by dinv[src])
        UNPACK_ACC(acc, raw);
    }
    int base = q * 16;
    for (int k = 0; k < cnt; k += 16) {
        int p = beg + k + c4;
        int sv = (p < end) ? csr_src[p] : 0;
        int m = min(16, cnt - k);
        int i = 0;
        for (; i + 8 <= m; i += 8) {
            int s0 = __shfl(sv, base + i + 0);
            int s1 = __shfl(sv, base + i + 1);
            int s2 = __shfl(sv, base + i + 2);
            int s3 = __shfl(sv, base + i + 3);
            int s4 = __shfl(sv, base + i + 4);
            int s5 = __shfl(sv, base + i + 5);
            int s6 = __shfl(sv, base + i + 6);
            int s7 = __shfl(sv, base + i + 7);
            float2 v0 = h2[(size_t)s0 * 16 + c4];
            float2 v1 = h2[(size_t)s1 * 16 + c4];
            float2 v2 = h2[(size_t)s2 * 16 + c4];
            float2 v3 = h2[(size_t)s3 * 16 + c4];
            float2 v4 = h2[(size_t)s4 * 16 + c4];
            float2 v5 = h2[(size_t)s5 * 16 + c4];
            float2 v6 = h2[(size_t)s6 * 16 + c4];
            float2 v7 = h2[(size_t)s7 * 16 + c4];
            UNPACK_ACC(acc, v0); UNPACK_ACC(acc, v1); UNPACK_ACC(acc, v2); UNPACK_ACC(acc, v3);
            UNPACK_ACC(acc, v4); UNPACK_ACC(acc, v5); UNPACK_ACC(acc, v6); UNPACK_ACC(acc, v7);
        }
        for (; i + 4 <= m; i += 4) {
            int s0 = __shfl(sv, base + i + 0);
            int s1 = __shfl(sv, base + i + 1);
            int s2 = __shfl(sv, base + i + 2);
            int s3 = __shfl(sv, base + i + 3);
            float2 v0 = h2[(size_t)s0 * 16 + c4];
            float2 v1 = h2[(size_t)s1 * 16 + c4];
            float2 v2 = h2[(size_t)s2 * 16 + c4];
            float2 v3 = h2[(size_t)s3 * 16 + c4];
            UNPACK_ACC(acc, v0); UNPACK_ACC(acc, v1); UNPACK_ACC(acc, v2); UNPACK_ACC(acc, v3);
        }
        for (; i < m; ++i) {
            int s = __shfl(sv, base + i);
            float2 hv = h2[(size_t)s * 16 + c4];
            UNPACK_ACC(acc, hv);
        }
    }
    if (active) {
        float dn = dinv[node];
        float4 bb = ((const float4*)b)[c4];
        float4 v;
        v.x = acc.x * dn + bb.x; v.y = acc.y * dn + bb.y;
        v.z = acc.z * dn + bb.z; v.w = acc.w * dn + bb.w;
        if (residual) {
            float4 r = ((const float4*)xprev)[(size_t)node * 16 + c4];
            v.x += r.x; v.y += r.y; v.z += r.z; v.w += r.w;
        }
        v.x = fmaxf(v.x, 0.f); v.y = fmaxf(v.y, 0.f);
        v.z = fmaxf(v.z, 0.f); v.w = fmaxf(v.w, 0.f);
        if (!project) {
            ((float4*)xout)[(size_t)node * 16 + c4] = v;
        } else {
            int cb = c4 * 4;
#pragma unroll
            for (int j = 0; j < 3; ++j) {
                float p = v.x * Wc[(cb + 0) * 3 + j] + v.y * Wc[(cb + 1) * 3 + j] +
                          v.z * Wc[(cb + 2) * 3 + j] + v.w * Wc[(cb + 3) * 3 + j];
                p += __shfl_down(p, 8);
                p += __shfl_down(p, 4);
                p += __shfl_down(p, 2);
                p += __shfl_down(p, 1);
                if (c4 == 0) outp[node * 3 + j] = p + bc[j];
            }
        }
    }
}

extern "C" void kernel_launch(void* const* d_in, const int* in_sizes, int n_in,
                              void* d_out, int out_size, void* d_ws, size_t ws_size,
                              hipStream_t stream) {
    const float* x  = (const float*)d_in[0];
    const int*   ei = (const int*)d_in[1];
    const float* Ws = (const float*)d_in[2];
    const float* bs = (const float*)d_in[3];
    const float* Wc = (const float*)d_in[4];
    const float* bc = (const float*)d_in[5];
    float* out = (float*)d_out;

    int E = in_sizes[1] / 2;
    const int* src = ei;
    const int* dst = ei + E;
    int nb = (NN + 255) / 256;

    char* wsb = (char*)d_ws;
    size_t off = 0;
    int*   deg     = (int*)(wsb + off); off += 100352 * 4;
    float* dinv    = (float*)(wsb + off); off += 100352 * 4;
    int*   row_ptr = (int*)(wsb + off); off += 100608 * 4;
    int*   cursor  = (int*)(wsb + off); off += 100352 * 4;
    int*   bsum    = (int*)(wsb + off); off += 512 * 4;
    int*   csr_src = (int*)(wsb + off); off += ((size_t)E + 256) * 4;
    float2* h      = (float2*)(wsb + off); off += (size_t)NN * HD * 2;  // fp16 h: N*64*2B
    float* xa      = (float*)(wsb + off); off += (size_t)NN * HD * 4;
    float* xb      = (float*)(wsb + off); off += (size_t)NN * HD * 4;

    // graph build
    hipMemsetAsync(deg, 0, NN * sizeof(int), stream);
    deg_kernel<<<(E + 255) / 256, 256, 0, stream>>>(dst, deg, E);
    dinv_kernel<<<(NN + 255) / 256, 256, 0, stream>>>(deg, dinv, NN);
    scanA_kernel<<<nb, 256, 0, stream>>>(deg, bsum, NN);
    scanB_kernel<<<1, 512, 0, stream>>>(bsum, row_ptr, nb, NN);
    scanC_kernel<<<nb, 256, 0, stream>>>(deg, bsum, row_ptr, cursor, NN);
    fill_kernel<<<(E + 255) / 256, 256, 0, stream>>>(src, dst, cursor, csr_src, E);

    // layers (ping-pong xa/xb); layer 3 fuses projection into agg epilogue
    const float* xin = x;
    float* bufs[2] = {xa, xb};
    int agg_blocks = ((NN + 3) / 4 * 64 + 255) / 256;  // 4 nodes per wave
    for (int l = 0; l < 4; ++l) {
        float* xout = bufs[l & 1];
        matmul64_kernel<<<(NN + 63) / 64, 256, 0, stream>>>(
            xin, Ws + (size_t)l * HD * HD, dinv, h, NN);
        agg_kernel<<<agg_blocks, 256, 0, stream>>>(
            h, row_ptr, csr_src, dinv, bs + l * HD, xin, xout,
            out, Wc, bc, NN, l > 0, l == 3);
        xin = xout;
    }
}